// Round 11
// baseline (148.594 us; speedup 1.0000x reference)
//
#include <hip/hip_runtime.h>
#include <hip/hip_bf16.h>

typedef __attribute__((ext_vector_type(8)))  float f8;
typedef __attribute__((ext_vector_type(16))) float f32x16;
typedef __attribute__((ext_vector_type(8)))  short bf8;

__device__ __forceinline__ short f2bf(float f) {
    unsigned u = __builtin_bit_cast(unsigned, f);
    u += 0x7fff + ((u >> 16) & 1);          // round-to-nearest-even
    return (short)(u >> 16);
}

// ---------------------------------------------------------------------------
// Prep: 64 blocks x 256 threads; each block redundantly computes row-sums +
// diag weights, then packs 512 of the 32768 fragment elements.
// Fragment order (32x32x16): f = kt*4+nt, kt=0..15, nt=0..3:
//   pre[(f*64 + lane)*8 + j] = Bmat[kt*16 + (lane>>5)*8 + j][nt*32 + (lane&31)]
//   Bmat[k][n] = k<128 ? U_w[n][k]
//                      : A_w[n][k-128]*dw[k-128]/dw[n] + (n==k-128)*(0.05-rs[n])
// (Validated: identical mapping passed in round 7 / v6, absmax 0.5.)
// ---------------------------------------------------------------------------
__global__ void nemon_prep(const float* __restrict__ Uw,
                           const float* __restrict__ Aw,
                           const float* __restrict__ dvec,
                           short* __restrict__ pre)
{
    __shared__ float rs[128], dwv[128];
    const int tid = threadIdx.x;
    if (tid < 128) {
        float s = 0.f;
        #pragma unroll 8
        for (int k = 0; k < 128; ++k) s += fabsf(Aw[tid * 128 + k]);
        rs[tid]  = s;
        dwv[tid] = expf(dvec[tid]);
    }
    __syncthreads();
    #pragma unroll
    for (int half = 0; half < 2; ++half) {
        const int e    = blockIdx.x * 512 + half * 256 + tid;
        const int j    = e & 7;
        const int lane = (e >> 3) & 63;
        const int f    = e >> 9;          // 0..63
        const int nt   = f & 3;
        const int kt   = f >> 2;          // 0..15
        const int k    = kt * 16 + (lane >> 5) * 8 + j;
        const int n    = nt * 32 + (lane & 31);
        float v;
        if (k < 128) {
            v = Uw[n * 128 + k];
        } else {
            const int k2 = k - 128;
            v = Aw[n * 128 + k2] * (dwv[k2] / dwv[n]);
            if (n == k2) v += 0.05f - rs[n];
        }
        pre[e] = f2bf(v);
    }
}

// ---------------------------------------------------------------------------
// Main v8: barrier-free (weights staged once into 64 KB LDS) + per-wave
// CONTINUOUS load streams. Each wave owns 4 grid-strided 32-row tiles.
// Staging regs are f8 (8 floats = one k-step per lane-half): xv[kt] covers
// k = kt*16 + hi*8 + 0..7 -- exactly the A-fragment k-mapping (OOB bug of
// v7/v7b eliminated). Refill of tile t+1's x issues right after tile t's
// x-half is consumed (ditto z), so loads stay in flight through the whole
// cvt+MFMA+store tail. Dense per-wave stores (32x32 C layout, m74/m101).
// ---------------------------------------------------------------------------
__global__ __launch_bounds__(512, 2) void nemon_main(
    const float* __restrict__ x,
    const float* __restrict__ z,
    const float* __restrict__ Ub,
    const short* __restrict__ pre,
    float* __restrict__ out)
{
    __shared__ short W[32768];            // 64 KB B-fragments = 4096 int4
    const int tid = threadIdx.x;

    {   // stage weights, linear: 4096 int4 / 512 thr = 8 each
        const int4* src = (const int4*)pre;
        int4*       dst = (int4*)W;
        #pragma unroll
        for (int i = 0; i < 8; ++i) dst[tid + 512 * i] = src[tid + 512 * i];
    }
    __syncthreads();                      // the only barrier

    const int wave = tid >> 6;
    const int lane = tid & 63;
    const int lo   = lane & 31;           // A row / C col (within 32-tiles)
    const int hi   = lane >> 5;           // k-half selector

    const int  wgid   = blockIdx.x * 8 + wave;   // 0..2047
    const long STRIDE = (long)2048 * 32 * 128;   // floats between a wave's tiles

    float ubv[4];
    #pragma unroll
    for (int nt = 0; nt < 4; ++nt) ubv[nt] = Ub[nt * 32 + lo];

    const long   R0 = (long)wgid * 32;
    const float* xr = x + (R0 + lo) * 128 + hi * 8;
    const float* zr = z + (R0 + lo) * 128 + hi * 8;

    // prologue: tile-0 x and z fully in flight (64+64 VGPRs)
    f8 xv[8], zv[8];
    #pragma unroll
    for (int i = 0; i < 8; ++i) xv[i] = *(const f8*)(xr + i * 16);
    #pragma unroll
    for (int i = 0; i < 8; ++i) zv[i] = *(const f8*)(zr + i * 16);

    #pragma unroll
    for (int it = 0; it < 4; ++it) {
        f32x16 acc[4];
        #pragma unroll
        for (int nt = 0; nt < 4; ++nt) {
            #pragma unroll
            for (int r = 0; r < 16; ++r) acc[nt][r] = ubv[nt];
        }

        // x-half: k-steps 0..7  (xv[kt] covers k = kt*16 + hi*8 + j)
        #pragma unroll
        for (int kt = 0; kt < 8; ++kt) {
            bf8 a = { f2bf(xv[kt][0]), f2bf(xv[kt][1]), f2bf(xv[kt][2]), f2bf(xv[kt][3]),
                      f2bf(xv[kt][4]), f2bf(xv[kt][5]), f2bf(xv[kt][6]), f2bf(xv[kt][7]) };
            #pragma unroll
            for (int nt = 0; nt < 4; ++nt) {
                bf8 b = *(const bf8*)&W[((kt * 4 + nt) * 64 + lane) * 8];
                acc[nt] = __builtin_amdgcn_mfma_f32_32x32x16_bf16(a, b, acc[nt], 0, 0, 0);
            }
        }
        // xv consumed -> refill with tile it+1's x (in flight from here on)
        if (it < 3) {
            #pragma unroll
            for (int i = 0; i < 8; ++i)
                xv[i] = *(const f8*)(xr + (long)(it + 1) * STRIDE + i * 16);
        }

        // z-half: k-steps 8..15
        #pragma unroll
        for (int kt = 0; kt < 8; ++kt) {
            bf8 a = { f2bf(zv[kt][0]), f2bf(zv[kt][1]), f2bf(zv[kt][2]), f2bf(zv[kt][3]),
                      f2bf(zv[kt][4]), f2bf(zv[kt][5]), f2bf(zv[kt][6]), f2bf(zv[kt][7]) };
            #pragma unroll
            for (int nt = 0; nt < 4; ++nt) {
                bf8 b = *(const bf8*)&W[(((kt + 8) * 4 + nt) * 64 + lane) * 8];
                acc[nt] = __builtin_amdgcn_mfma_f32_32x32x16_bf16(a, b, acc[nt], 0, 0, 0);
            }
        }
        // zv consumed -> refill with tile it+1's z
        if (it < 3) {
            #pragma unroll
            for (int i = 0; i < 8; ++i)
                zv[i] = *(const f8*)(zr + (long)(it + 1) * STRIDE + i * 16);
        }

        // stores: C layout col=lane&31, row=(reg&3)+8*(reg>>2)+4*hi
        // (2 x 128B dense segments per instruction)
        float* ob = out + (R0 + (long)it * 2048 * 32) * 128;
        #pragma unroll
        for (int reg = 0; reg < 16; ++reg) {
            const int rowA = (reg & 3) + 8 * (reg >> 2) + 4 * hi;
            #pragma unroll
            for (int nt = 0; nt < 4; ++nt)
                ob[rowA * 128 + nt * 32 + lo] = acc[nt][reg];
        }
    }
}

extern "C" void kernel_launch(void* const* d_in, const int* in_sizes, int n_in,
                              void* d_out, int out_size, void* d_ws, size_t ws_size,
                              hipStream_t stream) {
    const float* x  = (const float*)d_in[0];
    const float* z  = (const float*)d_in[1];
    const float* Uw = (const float*)d_in[2];
    const float* Ub = (const float*)d_in[3];
    const float* Aw = (const float*)d_in[4];
    const float* dv = (const float*)d_in[5];
    float* out = (float*)d_out;
    short* pre = (short*)d_ws;            // 64 KB prepacked weights

    nemon_prep<<<64, 256, 0, stream>>>(Uw, Aw, dv, pre);
    nemon_main<<<256, 512, 0, stream>>>(x, z, Ub, pre, out);
}

// Round 12
// 107.562 us; speedup vs baseline: 1.3815x; 1.3815x over previous
//
#include <hip/hip_runtime.h>
#include <hip/hip_bf16.h>

typedef __attribute__((ext_vector_type(8)))  float f8;
typedef __attribute__((ext_vector_type(16))) float f32x16;
typedef __attribute__((ext_vector_type(8)))  short bf8;

__device__ __forceinline__ short f2bf(float f) {
    unsigned u = __builtin_bit_cast(unsigned, f);
    u += 0x7fff + ((u >> 16) & 1);          // round-to-nearest-even
    return (short)(u >> 16);
}

// ---------------------------------------------------------------------------
// Prep (validated in rounds 7/11, absmax 0.5): fused B-matrix [256][128]
// packed as 32x32x16 MFMA B-fragments. f = kt*4+nt, kt=0..15, nt=0..3:
//   pre[(f*64 + lane)*8 + j] = Bmat[kt*16 + (lane>>5)*8 + j][nt*32 + (lane&31)]
//   Bmat[k][n] = k<128 ? U_w[n][k]
//                      : A_w[n][k-128]*dw[k-128]/dw[n] + (n==k-128)*(0.05-rs[n])
// ---------------------------------------------------------------------------
__global__ void nemon_prep(const float* __restrict__ Uw,
                           const float* __restrict__ Aw,
                           const float* __restrict__ dvec,
                           short* __restrict__ pre)
{
    __shared__ float rs[128], dwv[128];
    const int tid = threadIdx.x;
    if (tid < 128) {
        float s = 0.f;
        #pragma unroll 8
        for (int k = 0; k < 128; ++k) s += fabsf(Aw[tid * 128 + k]);
        rs[tid]  = s;
        dwv[tid] = expf(dvec[tid]);
    }
    __syncthreads();
    #pragma unroll
    for (int half = 0; half < 2; ++half) {
        const int e    = blockIdx.x * 512 + half * 256 + tid;
        const int j    = e & 7;
        const int lane = (e >> 3) & 63;
        const int f    = e >> 9;          // 0..63
        const int nt   = f & 3;
        const int kt   = f >> 2;          // 0..15
        const int k    = kt * 16 + (lane >> 5) * 8 + j;
        const int n    = nt * 32 + (lane & 31);
        float v;
        if (k < 128) {
            v = Uw[n * 128 + k];
        } else {
            const int k2 = k - 128;
            v = Aw[n * 128 + k2] * (dwv[k2] / dwv[n]);
            if (n == k2) v += 0.05f - rs[n];
        }
        pre[e] = f2bf(v);
    }
}

// ---------------------------------------------------------------------------
// Main v9: continuous per-wave load streams, SPILL-FREE.
// 256 threads = 4 waves/block; weights in 64 KB shared LDS (staged once,
// one barrier, conflict-free 16B/lane reads). Each wave owns 4 grid-strided
// 32-row tiles. Double register buffer A (x) / B (z): refill of the next
// tile's chunk issues immediately after the current chunk's last MFMA
// consumer, so each load has ~900 cy of compute+store to hide under and
// every wave keeps ~4-8 KB in flight continuously. launch_bounds(256,1)
// gives the register allocator room (live set ~210 VGPR) -- no spills,
// no prefetch-sinking. Dense per-wave stores (32x32 C layout, m74/m101).
// ---------------------------------------------------------------------------
__global__ __launch_bounds__(256, 1) void nemon_main(
    const float* __restrict__ x,
    const float* __restrict__ z,
    const float* __restrict__ Ub,
    const short* __restrict__ pre,
    float* __restrict__ out)
{
    __shared__ short W[32768];            // 64 KB B-fragments = 4096 int4
    const int tid = threadIdx.x;

    {   // stage weights, linear: 4096 int4 / 256 thr = 16 each
        const int4* src = (const int4*)pre;
        int4*       dst = (int4*)W;
        #pragma unroll
        for (int i = 0; i < 16; ++i) dst[tid + 256 * i] = src[tid + 256 * i];
    }
    __syncthreads();                      // the only barrier

    const int wave = tid >> 6;
    const int lane = tid & 63;
    const int lo   = lane & 31;           // A row / C col (within 32-tiles)
    const int hi   = lane >> 5;           // k-half selector

    const int  wgid = blockIdx.x * 4 + wave;     // 0..2047
    const long TROW = (long)2048 * 32;           // rows between a wave's tiles

    float ubv[4];
    #pragma unroll
    for (int nt = 0; nt < 4; ++nt) ubv[nt] = Ub[nt * 32 + lo];

    const long   R0 = (long)wgid * 32;
    const float* xr = x + (R0 + lo) * 128 + hi * 8;
    const float* zr = z + (R0 + lo) * 128 + hi * 8;

    // prologue: tile-0 x and z issued (128 VGPR in flight)
    f8 bufA[8], bufB[8];
    #pragma unroll
    for (int i = 0; i < 8; ++i) bufA[i] = *(const f8*)(xr + i * 16);
    #pragma unroll
    for (int i = 0; i < 8; ++i) bufB[i] = *(const f8*)(zr + i * 16);

    #pragma unroll
    for (int it = 0; it < 4; ++it) {
        f32x16 acc[4];
        #pragma unroll
        for (int nt = 0; nt < 4; ++nt) {
            #pragma unroll
            for (int r = 0; r < 16; ++r) acc[nt][r] = ubv[nt];
        }

        // x-phase: k-steps 0..7 (bufA[kt] covers k = kt*16 + hi*8 + j)
        #pragma unroll
        for (int kt = 0; kt < 8; ++kt) {
            bf8 a = { f2bf(bufA[kt][0]), f2bf(bufA[kt][1]), f2bf(bufA[kt][2]), f2bf(bufA[kt][3]),
                      f2bf(bufA[kt][4]), f2bf(bufA[kt][5]), f2bf(bufA[kt][6]), f2bf(bufA[kt][7]) };
            #pragma unroll
            for (int nt = 0; nt < 4; ++nt) {
                bf8 b = *(const bf8*)&W[((kt * 4 + nt) * 64 + lane) * 8];
                acc[nt] = __builtin_amdgcn_mfma_f32_32x32x16_bf16(a, b, acc[nt], 0, 0, 0);
            }
        }
        // bufA dead -> issue next tile's x (in flight through z-phase + store)
        if (it < 3) {
            const float* nx = xr + (long)(it + 1) * TROW * 128;
            #pragma unroll
            for (int i = 0; i < 8; ++i) bufA[i] = *(const f8*)(nx + i * 16);
        }

        // z-phase: k-steps 8..15
        #pragma unroll
        for (int kt = 0; kt < 8; ++kt) {
            bf8 a = { f2bf(bufB[kt][0]), f2bf(bufB[kt][1]), f2bf(bufB[kt][2]), f2bf(bufB[kt][3]),
                      f2bf(bufB[kt][4]), f2bf(bufB[kt][5]), f2bf(bufB[kt][6]), f2bf(bufB[kt][7]) };
            #pragma unroll
            for (int nt = 0; nt < 4; ++nt) {
                bf8 b = *(const bf8*)&W[(((kt + 8) * 4 + nt) * 64 + lane) * 8];
                acc[nt] = __builtin_amdgcn_mfma_f32_32x32x16_bf16(a, b, acc[nt], 0, 0, 0);
            }
        }
        // bufB dead -> issue next tile's z (in flight through store + next x-phase)
        if (it < 3) {
            const float* nz = zr + (long)(it + 1) * TROW * 128;
            #pragma unroll
            for (int i = 0; i < 8; ++i) bufB[i] = *(const f8*)(nz + i * 16);
        }

        // stores: C layout col=lane&31, row=(reg&3)+8*(reg>>2)+4*hi
        // (2 x 128B dense segments per instruction; WRITE_SIZE-exact in v6)
        float* ob = out + (R0 + (long)it * TROW) * 128;
        #pragma unroll
        for (int reg = 0; reg < 16; ++reg) {
            const int rowA = (reg & 3) + 8 * (reg >> 2) + 4 * hi;
            #pragma unroll
            for (int nt = 0; nt < 4; ++nt)
                ob[rowA * 128 + nt * 32 + lo] = acc[nt][reg];
        }
    }
}

extern "C" void kernel_launch(void* const* d_in, const int* in_sizes, int n_in,
                              void* d_out, int out_size, void* d_ws, size_t ws_size,
                              hipStream_t stream) {
    const float* x  = (const float*)d_in[0];
    const float* z  = (const float*)d_in[1];
    const float* Uw = (const float*)d_in[2];
    const float* Ub = (const float*)d_in[3];
    const float* Aw = (const float*)d_in[4];
    const float* dv = (const float*)d_in[5];
    float* out = (float*)d_out;
    short* pre = (short*)d_ws;            // 64 KB prepacked weights

    nemon_prep<<<64, 256, 0, stream>>>(Uw, Aw, dv, pre);
    nemon_main<<<512, 256, 0, stream>>>(x, z, Ub, pre, out);
}